// Round 5
// baseline (1892.483 us; speedup 1.0000x reference)
//
#include <hip/hip_runtime.h>
#include <hip/hip_bf16.h>

#define N_NODES 200000
#define N_EDGES 1200000
#define IN_DIM  128
#define HID     64
#define NGRAPH  1024
#define NCLS    6
#define BN_EPS  1e-5f

#define TILE_N   64          // nodes per GEMM block
#define XSTRIDE  132         // embed x-tile row stride (floats), bank-safe
#define ZS       68          // mlp z-tile row stride (floats), 16B-aligned, bank-safe

#define SCAN_CHUNK 1024
#define NBLK_SCAN ((N_NODES + SCAN_CHUNK - 1) / SCAN_CHUNK)   // 196

// ===========================================================================
// CSR build: deg histogram -> 3-step scan -> bucket scatter of src ids.
// ===========================================================================
__global__ __launch_bounds__(256) void hist_kernel(
    const int* __restrict__ dst, int* __restrict__ deg)
{
    const int e = blockIdx.x * 256 + threadIdx.x;
    if (e < N_EDGES) atomicAdd(&deg[dst[e]], 1);
}

__global__ __launch_bounds__(256) void scan_sum_kernel(
    const int* __restrict__ deg, int* __restrict__ bsum)
{
    __shared__ int sd[256];
    const int b = blockIdx.x, t = threadIdx.x;
    const int base = b * SCAN_CHUNK;
    int s = 0;
    #pragma unroll
    for (int i = 0; i < SCAN_CHUNK / 256; i++) {
        const int idx = base + t + i * 256;
        s += (idx < N_NODES) ? deg[idx] : 0;
    }
    sd[t] = s; __syncthreads();
    for (int off = 128; off > 0; off >>= 1) {
        if (t < off) sd[t] += sd[t + off];
        __syncthreads();
    }
    if (t == 0) bsum[b] = sd[0];
}

__global__ __launch_bounds__(256) void scan_block_kernel(
    const int* __restrict__ bsum, int* __restrict__ boff, int* __restrict__ offs)
{
    __shared__ int sd[256];
    const int t = threadIdx.x;
    const int v = (t < NBLK_SCAN) ? bsum[t] : 0;
    sd[t] = v; __syncthreads();
    for (int off = 1; off < 256; off <<= 1) {
        const int u = (t >= off) ? sd[t - off] : 0;
        __syncthreads();
        sd[t] += u;
        __syncthreads();
    }
    if (t < NBLK_SCAN) boff[t] = sd[t] - v;   // exclusive
    if (t == 0) offs[N_NODES] = N_EDGES;
}

__global__ __launch_bounds__(256) void scan_scatter_kernel(
    const int* __restrict__ deg, const int* __restrict__ boff, int* __restrict__ offs)
{
    __shared__ int sd[256];
    const int b = blockIdx.x, t = threadIdx.x;
    const int base = b * SCAN_CHUNK + t * 4;
    int d0 = 0, d1 = 0, d2 = 0, d3 = 0;
    if (base + 0 < N_NODES) d0 = deg[base + 0];
    if (base + 1 < N_NODES) d1 = deg[base + 1];
    if (base + 2 < N_NODES) d2 = deg[base + 2];
    if (base + 3 < N_NODES) d3 = deg[base + 3];
    const int ts = d0 + d1 + d2 + d3;
    sd[t] = ts; __syncthreads();
    for (int off = 1; off < 256; off <<= 1) {
        const int u = (t >= off) ? sd[t - off] : 0;
        __syncthreads();
        sd[t] += u;
        __syncthreads();
    }
    const int excl = sd[t] - ts + boff[b];
    if (base + 0 < N_NODES) offs[base + 0] = excl;
    if (base + 1 < N_NODES) offs[base + 1] = excl + d0;
    if (base + 2 < N_NODES) offs[base + 2] = excl + d0 + d1;
    if (base + 3 < N_NODES) offs[base + 3] = excl + d0 + d1 + d2;
}

__global__ __launch_bounds__(256) void bucket_kernel(
    const int* __restrict__ src, const int* __restrict__ dst,
    int* __restrict__ cursor, int* __restrict__ csr_src)
{
    const int e = blockIdx.x * 256 + threadIdx.x;
    if (e < N_EDGES) {
        const int pos = atomicAdd(&cursor[dst[e]], 1);
        csr_src[pos] = src[e];
    }
}

// ===========================================================================
// Embed: h0 = relu(bn(x @ W + b)). Register-blocked LDS GEMM, K=128 in halves.
// ===========================================================================
__global__ __launch_bounds__(256) void embed_kernel(
    const float* __restrict__ x,      // [N,128]
    const float* __restrict__ w,      // [128,64]
    const float* __restrict__ bias,
    const float* __restrict__ bn_g, const float* __restrict__ bn_b,
    const float* __restrict__ bn_m, const float* __restrict__ bn_v,
    float* __restrict__ h)            // [N,64]
{
    __shared__ float Z[TILE_N * XSTRIDE];   // 33792 B
    __shared__ float Wl[64 * HID];          // 16384 B
    const int t = threadIdx.x;
    const int cgrp = t & 15, ngrp = t >> 4;
    const int c0 = cgrp * 4;
    const int base = blockIdx.x * TILE_N;

    #pragma unroll
    for (int i = 0; i < 8; i++) {
        const int idx = t + i * 256;            // 0..2047
        const int n = idx >> 5, k4 = idx & 31;
        *(float4*)(&Z[n * XSTRIDE + k4 * 4]) =
            *(const float4*)(x + (size_t)(base + n) * IN_DIM + k4 * 4);
    }

    float scale[4], shift[4];
    #pragma unroll
    for (int cc = 0; cc < 4; cc++) {
        const int c = c0 + cc;
        const float s = bn_g[c] * rsqrtf(bn_v[c] + BN_EPS);
        scale[cc] = s;
        shift[cc] = bias[c] * s + bn_b[c] - bn_m[c] * s;
    }

    float acc[4][4] = {};
    for (int kh = 0; kh < 2; kh++) {
        __syncthreads();
        #pragma unroll
        for (int i = 0; i < 4; i++) {
            const int idx = t + i * 256;
            const int k = idx >> 4, k4 = idx & 15;
            *(float4*)(&Wl[k * HID + k4 * 4]) =
                *(const float4*)(w + (size_t)(kh * 64 + k) * HID + k4 * 4);
        }
        __syncthreads();

        #pragma unroll
        for (int k4 = 0; k4 < 16; k4++) {
            float4 zv[4], wv[4];
            #pragma unroll
            for (int j = 0; j < 4; j++)
                zv[j] = *(const float4*)(&Z[(ngrp + 16 * j) * XSTRIDE + (kh * 16 + k4) * 4]);
            #pragma unroll
            for (int i = 0; i < 4; i++)
                wv[i] = *(const float4*)(&Wl[(k4 * 4 + i) * HID + c0]);
            #pragma unroll
            for (int j = 0; j < 4; j++) {
                const float z0 = zv[j].x, z1 = zv[j].y, z2 = zv[j].z, z3 = zv[j].w;
                acc[j][0] += z0 * wv[0].x + z1 * wv[1].x + z2 * wv[2].x + z3 * wv[3].x;
                acc[j][1] += z0 * wv[0].y + z1 * wv[1].y + z2 * wv[2].y + z3 * wv[3].y;
                acc[j][2] += z0 * wv[0].z + z1 * wv[1].z + z2 * wv[2].z + z3 * wv[3].z;
                acc[j][3] += z0 * wv[0].w + z1 * wv[1].w + z2 * wv[2].w + z3 * wv[3].w;
            }
        }
    }

    #pragma unroll
    for (int j = 0; j < 4; j++) {
        const int n = base + ngrp + 16 * j;
        float4 o;
        o.x = fmaxf(acc[j][0] * scale[0] + shift[0], 0.f);
        o.y = fmaxf(acc[j][1] * scale[1] + shift[1], 0.f);
        o.z = fmaxf(acc[j][2] * scale[2] + shift[2], 0.f);
        o.w = fmaxf(acc[j][3] * scale[3] + shift[3], 0.f);
        *(float4*)(h + (size_t)n * HID + c0) = o;
    }
}

// ===========================================================================
// Fused GIN layer: edge-centric CSR gather with LDS f32 atomics, then two
// register-blocked GEMMs. CSR is dst-sorted so each 64-node tile owns a
// contiguous edge segment; wave w walks the segment of its 16 nodes with
// lane = (sub-edge 0..3, chan-quad 0..15): 4 rows per load instr, no serial
// dependency chain -> loads pipeline freely.
// ===========================================================================
__global__ __launch_bounds__(256) void agg_mlp_kernel(
    const float* __restrict__ hin, float* __restrict__ hout,
    const int* __restrict__ offs, const int* __restrict__ csr,
    const float* __restrict__ w1, const float* __restrict__ b1,
    const float* __restrict__ g1, const float* __restrict__ bb1,
    const float* __restrict__ m1, const float* __restrict__ v1,
    const float* __restrict__ w2, const float* __restrict__ b2,
    const float* __restrict__ g2, const float* __restrict__ bb2,
    const float* __restrict__ m2, const float* __restrict__ v2)
{
    __shared__ float Z[TILE_N * ZS];        // 17408 B
    __shared__ float Wl[HID * HID];         // 16384 B
    __shared__ int   OF[TILE_N + 1];        // 260 B
    const int t = threadIdx.x;
    const int lane = t & 63, w = t >> 6;
    const int sub = lane >> 4, cq = lane & 15;
    const int cgrp = t & 15, ngrp = t >> 4;
    const int c0 = cgrp * 4;
    const int base = blockIdx.x * TILE_N;

    // stage W1
    #pragma unroll
    for (int i = 0; i < 4; i++) {
        const int idx = t + i * 256;
        const int k = idx >> 4, k4 = idx & 15;
        *(float4*)(&Wl[k * HID + k4 * 4]) = *(const float4*)(w1 + (size_t)k * HID + k4 * 4);
    }
    // stage CSR offsets for this tile
    if (t <= TILE_N) OF[t] = offs[base + t];
    // stage self rows: Z[n] = hin[base+n]  (coalesced, 64 rows x 16 float4)
    #pragma unroll
    for (int i = 0; i < 4; i++) {
        const int idx = t + i * 256;
        const int n = idx >> 4, k4 = idx & 15;
        *(float4*)(&Z[n * ZS + k4 * 4]) =
            *(const float4*)(hin + (size_t)(base + n) * HID + k4 * 4);
    }
    __syncthreads();

    // edge-centric gather: wave w covers edges of nodes [w*16, w*16+16)
    {
        const int segStart = OF[w * 16], segEnd = OF[w * 16 + 16];
        int nn = w * 16;
        int nxt = OF[nn + 1];
        int e = segStart + sub;

        #define AGG_BODY(EV)                                                   \
            {                                                                  \
                const int ee = (EV);                                           \
                while (ee >= nxt) { nn++; nxt = OF[nn + 1]; }                  \
                const int s = csr[ee];                                         \
                const float4 v = *(const float4*)(hin + (size_t)s * HID + cq * 4); \
                atomicAdd(&Z[nn * ZS + cq * 4 + 0], v.x);                      \
                atomicAdd(&Z[nn * ZS + cq * 4 + 1], v.y);                      \
                atomicAdd(&Z[nn * ZS + cq * 4 + 2], v.z);                      \
                atomicAdd(&Z[nn * ZS + cq * 4 + 3], v.w);                      \
            }

        for (; e + 4 < segEnd; e += 8) {   // 2x unroll: 2 row loads in flight
            AGG_BODY(e);
            AGG_BODY(e + 4);
        }
        if (e < segEnd) AGG_BODY(e);
        #undef AGG_BODY
    }

    float s1c[4], c1c[4], s2c[4], c2c[4];
    #pragma unroll
    for (int cc = 0; cc < 4; cc++) {
        const int c = c0 + cc;
        const float sa = g1[c] * rsqrtf(v1[c] + BN_EPS);
        s1c[cc] = sa; c1c[cc] = b1[c] * sa + bb1[c] - m1[c] * sa;
        const float sb = g2[c] * rsqrtf(v2[c] + BN_EPS);
        s2c[cc] = sb; c2c[cc] = b2[c] * sb + bb2[c] - m2[c] * sb;
    }
    __syncthreads();   // all atomics done; Z complete

    // GEMM1
    float acc1[4][4] = {};
    #pragma unroll
    for (int k4 = 0; k4 < 16; k4++) {
        float4 zv[4], wv[4];
        #pragma unroll
        for (int j = 0; j < 4; j++)
            zv[j] = *(const float4*)(&Z[(ngrp + 16 * j) * ZS + k4 * 4]);
        #pragma unroll
        for (int i = 0; i < 4; i++)
            wv[i] = *(const float4*)(&Wl[(k4 * 4 + i) * HID + c0]);
        #pragma unroll
        for (int j = 0; j < 4; j++) {
            const float z0 = zv[j].x, z1 = zv[j].y, z2 = zv[j].z, z3 = zv[j].w;
            acc1[j][0] += z0 * wv[0].x + z1 * wv[1].x + z2 * wv[2].x + z3 * wv[3].x;
            acc1[j][1] += z0 * wv[0].y + z1 * wv[1].y + z2 * wv[2].y + z3 * wv[3].y;
            acc1[j][2] += z0 * wv[0].z + z1 * wv[1].z + z2 * wv[2].z + z3 * wv[3].z;
            acc1[j][3] += z0 * wv[0].w + z1 * wv[1].w + z2 * wv[2].w + z3 * wv[3].w;
        }
    }
    __syncthreads();   // GEMM1 reads of Z/Wl done

    // t1 = relu(bn1(.)) back into Z; stage W2
    #pragma unroll
    for (int j = 0; j < 4; j++) {
        const int n = ngrp + 16 * j;
        float4 o;
        o.x = fmaxf(acc1[j][0] * s1c[0] + c1c[0], 0.f);
        o.y = fmaxf(acc1[j][1] * s1c[1] + c1c[1], 0.f);
        o.z = fmaxf(acc1[j][2] * s1c[2] + c1c[2], 0.f);
        o.w = fmaxf(acc1[j][3] * s1c[3] + c1c[3], 0.f);
        *(float4*)(&Z[n * ZS + c0]) = o;
    }
    #pragma unroll
    for (int i = 0; i < 4; i++) {
        const int idx = t + i * 256;
        const int k = idx >> 4, k4 = idx & 15;
        *(float4*)(&Wl[k * HID + k4 * 4]) = *(const float4*)(w2 + (size_t)k * HID + k4 * 4);
    }
    __syncthreads();

    // GEMM2
    float acc2[4][4] = {};
    #pragma unroll
    for (int k4 = 0; k4 < 16; k4++) {
        float4 zv[4], wv[4];
        #pragma unroll
        for (int j = 0; j < 4; j++)
            zv[j] = *(const float4*)(&Z[(ngrp + 16 * j) * ZS + k4 * 4]);
        #pragma unroll
        for (int i = 0; i < 4; i++)
            wv[i] = *(const float4*)(&Wl[(k4 * 4 + i) * HID + c0]);
        #pragma unroll
        for (int j = 0; j < 4; j++) {
            const float z0 = zv[j].x, z1 = zv[j].y, z2 = zv[j].z, z3 = zv[j].w;
            acc2[j][0] += z0 * wv[0].x + z1 * wv[1].x + z2 * wv[2].x + z3 * wv[3].x;
            acc2[j][1] += z0 * wv[0].y + z1 * wv[1].y + z2 * wv[2].y + z3 * wv[3].y;
            acc2[j][2] += z0 * wv[0].z + z1 * wv[1].z + z2 * wv[2].z + z3 * wv[3].z;
            acc2[j][3] += z0 * wv[0].w + z1 * wv[1].w + z2 * wv[2].w + z3 * wv[3].w;
        }
    }

    #pragma unroll
    for (int j = 0; j < 4; j++) {
        const int n = base + ngrp + 16 * j;
        float4 o;
        o.x = fmaxf(acc2[j][0] * s2c[0] + c2c[0], 0.f);
        o.y = fmaxf(acc2[j][1] * s2c[1] + c2c[1], 0.f);
        o.z = fmaxf(acc2[j][2] * s2c[2] + c2c[2], 0.f);
        o.w = fmaxf(acc2[j][3] * s2c[3] + c2c[3], 0.f);
        *(float4*)(hout + (size_t)n * HID + c0) = o;
    }
}

// ===========================================================================
// Pool: batch sorted; register run-accumulation, one atomic per transition.
// ===========================================================================
__global__ __launch_bounds__(256) void pool_kernel(
    const float* __restrict__ h, const int* __restrict__ batch,
    float* __restrict__ pooled, float* __restrict__ cnt)
{
    const int CHUNK = 256;
    const int wid = (blockIdx.x * 256 + threadIdx.x) >> 6;
    const int lane = threadIdx.x & 63;
    const int start = wid * CHUNK;
    if (start >= N_NODES) return;
    const int end = (start + CHUNK < N_NODES) ? (start + CHUNK) : N_NODES;
    int cur = batch[start];
    float acc = 0.f, c = 0.f;
    for (int n = start; n < end; n++) {
        const int g = batch[n];
        if (g != cur) {
            atomicAdd(&pooled[(size_t)cur * HID + lane], acc);
            if (lane == 0) atomicAdd(&cnt[cur], c);
            cur = g; acc = 0.f; c = 0.f;
        }
        acc += h[(size_t)n * HID + lane];
        c += 1.f;
    }
    atomicAdd(&pooled[(size_t)cur * HID + lane], acc);
    if (lane == 0) atomicAdd(&cnt[cur], c);
}

// ===========================================================================
// Classifier
// ===========================================================================
__global__ __launch_bounds__(64) void cls_kernel(
    const float* __restrict__ pooled, const float* __restrict__ cnt,
    const float* __restrict__ w1, const float* __restrict__ b1,
    const float* __restrict__ w2, const float* __restrict__ b2,
    float* __restrict__ out)
{
    const int g = blockIdx.x;
    const int lane = threadIdx.x;
    const float c = cnt[g];
    const float p = pooled[(size_t)g * HID + lane] / fmaxf(c, 1.f);
    float acc = (lane < 32) ? b1[lane] : 0.f;
    #pragma unroll
    for (int k = 0; k < 64; k++) {
        const float pk = __shfl(p, k, 64);
        if (lane < 32) acc += pk * w1[k * 32 + lane];
    }
    const float hmid = fmaxf(acc, 0.f);
    float acc2 = (lane < NCLS) ? b2[lane] : 0.f;
    #pragma unroll
    for (int k = 0; k < 32; k++) {
        const float hk = __shfl(hmid, k, 64);
        if (lane < NCLS) acc2 += hk * w2[k * NCLS + lane];
    }
    if (lane < NCLS) out[(size_t)g * NCLS + lane] = acc2;
}

// ===========================================================================
extern "C" void kernel_launch(void* const* d_in, const int* in_sizes, int n_in,
                              void* d_out, int out_size, void* d_ws, size_t ws_size,
                              hipStream_t stream) {
    const float* x     = (const float*)d_in[0];
    const int*   ei    = (const int*)d_in[1];            // [2,E]
    const int*   batch = (const int*)d_in[2];
    const float* emb_w = (const float*)d_in[3];
    const float* emb_b = (const float*)d_in[4];
    const float* ibn_g = (const float*)d_in[5];
    const float* ibn_b = (const float*)d_in[6];
    const float* ibn_m = (const float*)d_in[7];
    const float* ibn_v = (const float*)d_in[8];
    const float* fc1_w = (const float*)d_in[9];
    const float* fc1_b = (const float*)d_in[10];
    const float* mbn_g = (const float*)d_in[11];
    const float* mbn_b = (const float*)d_in[12];
    const float* mbn_m = (const float*)d_in[13];
    const float* mbn_v = (const float*)d_in[14];
    const float* fc2_w = (const float*)d_in[15];
    const float* fc2_b = (const float*)d_in[16];
    const float* obn_g = (const float*)d_in[17];
    const float* obn_b = (const float*)d_in[18];
    const float* obn_m = (const float*)d_in[19];
    const float* obn_v = (const float*)d_in[20];
    const float* cls1w = (const float*)d_in[21];
    const float* cls1b = (const float*)d_in[22];
    const float* cls2w = (const float*)d_in[23];
    const float* cls2b = (const float*)d_in[24];

    float* h0     = (float*)d_ws;                        // 12.8M floats
    float* h1     = h0 + (size_t)N_NODES * HID;          // 12.8M floats
    float* pooled = h1 + (size_t)N_NODES * HID;          // 65536
    float* cnt    = pooled + NGRAPH * HID;               // 1024
    int*   deg    = (int*)(cnt + NGRAPH);                // 200000 (reused as cursor)
    int*   offs   = deg + N_NODES;                       // 200001
    int*   bsum   = offs + (N_NODES + 1);                // 196
    int*   boff   = bsum + NBLK_SCAN;                    // 196
    int*   csr    = boff + NBLK_SCAN;                    // 1.2M

    const int* src = ei;
    const int* dst = ei + N_EDGES;

    // ---- CSR build (once, reused by all 3 layers) ----
    hipMemsetAsync(deg, 0, N_NODES * sizeof(int), stream);
    hipMemsetAsync(pooled, 0, (size_t)(NGRAPH * HID + NGRAPH) * sizeof(float), stream);
    hist_kernel<<<(N_EDGES + 255) / 256, 256, 0, stream>>>(dst, deg);
    scan_sum_kernel<<<NBLK_SCAN, 256, 0, stream>>>(deg, bsum);
    scan_block_kernel<<<1, 256, 0, stream>>>(bsum, boff, offs);
    scan_scatter_kernel<<<NBLK_SCAN, 256, 0, stream>>>(deg, boff, offs);
    hipMemcpyAsync(deg, offs, N_NODES * sizeof(int), hipMemcpyDeviceToDevice, stream);
    bucket_kernel<<<(N_EDGES + 255) / 256, 256, 0, stream>>>(src, dst, deg, csr);

    // ---- network ----
    const int gemm_blocks = N_NODES / TILE_N;   // 3125
    embed_kernel<<<gemm_blocks, 256, 0, stream>>>(x, emb_w, emb_b,
                                                  ibn_g, ibn_b, ibn_m, ibn_v, h0);

    const float* hin = h0;
    float* hout = h1;
    for (int i = 0; i < 3; i++) {
        agg_mlp_kernel<<<gemm_blocks, 256, 0, stream>>>(
            hin, hout, offs, csr,
            fc1_w + i * HID * HID, fc1_b + i * HID,
            mbn_g + i * HID, mbn_b + i * HID, mbn_m + i * HID, mbn_v + i * HID,
            fc2_w + i * HID * HID, fc2_b + i * HID,
            obn_g + i * HID, obn_b + i * HID, obn_m + i * HID, obn_v + i * HID);
        const float* tmp = hin; hin = hout; hout = (float*)tmp;
    }
    // after 3 layers: result in h1 (h0->h1->h0->h1)

    const int pool_waves = (N_NODES + 255) / 256;
    pool_kernel<<<(pool_waves + 3) / 4, 256, 0, stream>>>(h1, batch, pooled, cnt);

    cls_kernel<<<NGRAPH, 64, 0, stream>>>(pooled, cnt, cls1w, cls1b, cls2w, cls2b,
                                          (float*)d_out);
}

// Round 6
// 1135.316 us; speedup vs baseline: 1.6669x; 1.6669x over previous
//
#include <hip/hip_runtime.h>
#include <hip/hip_bf16.h>

#define N_NODES 200000
#define N_EDGES 1200000
#define IN_DIM  128
#define HID     64
#define NGRAPH  1024
#define NCLS    6
#define BN_EPS  1e-5f

#define TILE_N   64          // nodes per GEMM block
#define XSTRIDE  132         // embed x-tile row stride (floats), bank-safe
#define ZS       68          // mlp z-tile row stride (floats), 16B-aligned, bank-safe

#define SCAN_CHUNK 1024
#define NBLK_SCAN ((N_NODES + SCAN_CHUNK - 1) / SCAN_CHUNK)   // 196

// ===========================================================================
// CSR build: deg histogram -> 3-step scan -> bucket scatter of src ids.
// ===========================================================================
__global__ __launch_bounds__(256) void hist_kernel(
    const int* __restrict__ dst, int* __restrict__ deg)
{
    const int e = blockIdx.x * 256 + threadIdx.x;
    if (e < N_EDGES) atomicAdd(&deg[dst[e]], 1);
}

__global__ __launch_bounds__(256) void scan_sum_kernel(
    const int* __restrict__ deg, int* __restrict__ bsum)
{
    __shared__ int sd[256];
    const int b = blockIdx.x, t = threadIdx.x;
    const int base = b * SCAN_CHUNK;
    int s = 0;
    #pragma unroll
    for (int i = 0; i < SCAN_CHUNK / 256; i++) {
        const int idx = base + t + i * 256;
        s += (idx < N_NODES) ? deg[idx] : 0;
    }
    sd[t] = s; __syncthreads();
    for (int off = 128; off > 0; off >>= 1) {
        if (t < off) sd[t] += sd[t + off];
        __syncthreads();
    }
    if (t == 0) bsum[b] = sd[0];
}

__global__ __launch_bounds__(256) void scan_block_kernel(
    const int* __restrict__ bsum, int* __restrict__ boff, int* __restrict__ offs)
{
    __shared__ int sd[256];
    const int t = threadIdx.x;
    const int v = (t < NBLK_SCAN) ? bsum[t] : 0;
    sd[t] = v; __syncthreads();
    for (int off = 1; off < 256; off <<= 1) {
        const int u = (t >= off) ? sd[t - off] : 0;
        __syncthreads();
        sd[t] += u;
        __syncthreads();
    }
    if (t < NBLK_SCAN) boff[t] = sd[t] - v;   // exclusive
    if (t == 0) offs[N_NODES] = N_EDGES;
}

__global__ __launch_bounds__(256) void scan_scatter_kernel(
    const int* __restrict__ deg, const int* __restrict__ boff, int* __restrict__ offs)
{
    __shared__ int sd[256];
    const int b = blockIdx.x, t = threadIdx.x;
    const int base = b * SCAN_CHUNK + t * 4;
    int d0 = 0, d1 = 0, d2 = 0, d3 = 0;
    if (base + 0 < N_NODES) d0 = deg[base + 0];
    if (base + 1 < N_NODES) d1 = deg[base + 1];
    if (base + 2 < N_NODES) d2 = deg[base + 2];
    if (base + 3 < N_NODES) d3 = deg[base + 3];
    const int ts = d0 + d1 + d2 + d3;
    sd[t] = ts; __syncthreads();
    for (int off = 1; off < 256; off <<= 1) {
        const int u = (t >= off) ? sd[t - off] : 0;
        __syncthreads();
        sd[t] += u;
        __syncthreads();
    }
    const int excl = sd[t] - ts + boff[b];
    if (base + 0 < N_NODES) offs[base + 0] = excl;
    if (base + 1 < N_NODES) offs[base + 1] = excl + d0;
    if (base + 2 < N_NODES) offs[base + 2] = excl + d0 + d1;
    if (base + 3 < N_NODES) offs[base + 3] = excl + d0 + d1 + d2;
}

__global__ __launch_bounds__(256) void bucket_kernel(
    const int* __restrict__ src, const int* __restrict__ dst,
    int* __restrict__ cursor, int* __restrict__ csr_src)
{
    const int e = blockIdx.x * 256 + threadIdx.x;
    if (e < N_EDGES) {
        const int pos = atomicAdd(&cursor[dst[e]], 1);
        csr_src[pos] = src[e];
    }
}

// ===========================================================================
// Embed: h0 = relu(bn(x @ W + b)). Register-blocked LDS GEMM, K=128 in halves.
// ===========================================================================
__global__ __launch_bounds__(256) void embed_kernel(
    const float* __restrict__ x,      // [N,128]
    const float* __restrict__ w,      // [128,64]
    const float* __restrict__ bias,
    const float* __restrict__ bn_g, const float* __restrict__ bn_b,
    const float* __restrict__ bn_m, const float* __restrict__ bn_v,
    float* __restrict__ h)            // [N,64]
{
    __shared__ float Z[TILE_N * XSTRIDE];   // 33792 B
    __shared__ float Wl[64 * HID];          // 16384 B
    const int t = threadIdx.x;
    const int cgrp = t & 15, ngrp = t >> 4;
    const int c0 = cgrp * 4;
    const int base = blockIdx.x * TILE_N;

    #pragma unroll
    for (int i = 0; i < 8; i++) {
        const int idx = t + i * 256;            // 0..2047
        const int n = idx >> 5, k4 = idx & 31;
        *(float4*)(&Z[n * XSTRIDE + k4 * 4]) =
            *(const float4*)(x + (size_t)(base + n) * IN_DIM + k4 * 4);
    }

    float scale[4], shift[4];
    #pragma unroll
    for (int cc = 0; cc < 4; cc++) {
        const int c = c0 + cc;
        const float s = bn_g[c] * rsqrtf(bn_v[c] + BN_EPS);
        scale[cc] = s;
        shift[cc] = bias[c] * s + bn_b[c] - bn_m[c] * s;
    }

    float acc[4][4] = {};
    for (int kh = 0; kh < 2; kh++) {
        __syncthreads();
        #pragma unroll
        for (int i = 0; i < 4; i++) {
            const int idx = t + i * 256;
            const int k = idx >> 4, k4 = idx & 15;
            *(float4*)(&Wl[k * HID + k4 * 4]) =
                *(const float4*)(w + (size_t)(kh * 64 + k) * HID + k4 * 4);
        }
        __syncthreads();

        #pragma unroll
        for (int k4 = 0; k4 < 16; k4++) {
            float4 zv[4], wv[4];
            #pragma unroll
            for (int j = 0; j < 4; j++)
                zv[j] = *(const float4*)(&Z[(ngrp + 16 * j) * XSTRIDE + (kh * 16 + k4) * 4]);
            #pragma unroll
            for (int i = 0; i < 4; i++)
                wv[i] = *(const float4*)(&Wl[(k4 * 4 + i) * HID + c0]);
            #pragma unroll
            for (int j = 0; j < 4; j++) {
                const float z0 = zv[j].x, z1 = zv[j].y, z2 = zv[j].z, z3 = zv[j].w;
                acc[j][0] += z0 * wv[0].x + z1 * wv[1].x + z2 * wv[2].x + z3 * wv[3].x;
                acc[j][1] += z0 * wv[0].y + z1 * wv[1].y + z2 * wv[2].y + z3 * wv[3].y;
                acc[j][2] += z0 * wv[0].z + z1 * wv[1].z + z2 * wv[2].z + z3 * wv[3].z;
                acc[j][3] += z0 * wv[0].w + z1 * wv[1].w + z2 * wv[2].w + z3 * wv[3].w;
            }
        }
    }

    #pragma unroll
    for (int j = 0; j < 4; j++) {
        const int n = base + ngrp + 16 * j;
        float4 o;
        o.x = fmaxf(acc[j][0] * scale[0] + shift[0], 0.f);
        o.y = fmaxf(acc[j][1] * scale[1] + shift[1], 0.f);
        o.z = fmaxf(acc[j][2] * scale[2] + shift[2], 0.f);
        o.w = fmaxf(acc[j][3] * scale[3] + shift[3], 0.f);
        *(float4*)(h + (size_t)n * HID + c0) = o;
    }
}

// ===========================================================================
// Fused GIN layer: node-centric gather with 16 INTERLEAVED independent
// accumulator chains per wave (lane = channel), then two register-blocked
// GEMMs. All loop bounds are wave-uniform (scalar branches, no divergence);
// each pass issues up to 16 independent csr + 16 independent row loads
// before any wait -> pass latency ~ one load latency, not one per edge.
// No atomics anywhere.
// ===========================================================================
__global__ __launch_bounds__(256) void agg_mlp_kernel(
    const float* __restrict__ hin, float* __restrict__ hout,
    const int* __restrict__ offs, const int* __restrict__ csr,
    const float* __restrict__ w1, const float* __restrict__ b1,
    const float* __restrict__ g1, const float* __restrict__ bb1,
    const float* __restrict__ m1, const float* __restrict__ v1,
    const float* __restrict__ w2, const float* __restrict__ b2,
    const float* __restrict__ g2, const float* __restrict__ bb2,
    const float* __restrict__ m2, const float* __restrict__ v2)
{
    __shared__ float Z[TILE_N * ZS];        // 17408 B
    __shared__ float Wl[HID * HID];         // 16384 B
    __shared__ int   OF[TILE_N + 1];        // 260 B
    const int t = threadIdx.x;
    const int lane = t & 63, w = t >> 6;
    const int cgrp = t & 15, ngrp = t >> 4;
    const int c0 = cgrp * 4;
    const int base = blockIdx.x * TILE_N;

    // stage W1
    #pragma unroll
    for (int i = 0; i < 4; i++) {
        const int idx = t + i * 256;
        const int k = idx >> 4, k4 = idx & 15;
        *(float4*)(&Wl[k * HID + k4 * 4]) = *(const float4*)(w1 + (size_t)k * HID + k4 * 4);
    }
    // stage CSR offsets for this tile
    if (t <= TILE_N) OF[t] = offs[base + t];
    __syncthreads();

    // gather: wave w owns nodes [w*16, w*16+16), all 16 chains interleaved
    {
        const int nb = w * 16;
        float acc[16];
        int e[16], en[16];
        #pragma unroll
        for (int i = 0; i < 16; i++) {
            e[i]  = OF[nb + i];
            en[i] = OF[nb + i + 1];
            acc[i] = hin[(size_t)(base + nb + i) * HID + lane];   // self row
        }
        for (;;) {
            bool any = false;
            #pragma unroll
            for (int i = 0; i < 16; i++) any |= (e[i] < en[i]);
            if (!any) break;
            int s[16];
            #pragma unroll
            for (int i = 0; i < 16; i++)
                if (e[i] < en[i]) s[i] = csr[e[i]];               // wave-uniform branch
            float v[16];
            #pragma unroll
            for (int i = 0; i < 16; i++)
                if (e[i] < en[i]) v[i] = hin[(size_t)s[i] * HID + lane];
            #pragma unroll
            for (int i = 0; i < 16; i++)
                if (e[i] < en[i]) { acc[i] += v[i]; e[i]++; }
        }
        #pragma unroll
        for (int i = 0; i < 16; i++)
            Z[(nb + i) * ZS + lane] = acc[i];
    }

    float s1c[4], c1c[4], s2c[4], c2c[4];
    #pragma unroll
    for (int cc = 0; cc < 4; cc++) {
        const int c = c0 + cc;
        const float sa = g1[c] * rsqrtf(v1[c] + BN_EPS);
        s1c[cc] = sa; c1c[cc] = b1[c] * sa + bb1[c] - m1[c] * sa;
        const float sb = g2[c] * rsqrtf(v2[c] + BN_EPS);
        s2c[cc] = sb; c2c[cc] = b2[c] * sb + bb2[c] - m2[c] * sb;
    }
    __syncthreads();   // Z complete

    // GEMM1
    float acc1[4][4] = {};
    #pragma unroll
    for (int k4 = 0; k4 < 16; k4++) {
        float4 zv[4], wv[4];
        #pragma unroll
        for (int j = 0; j < 4; j++)
            zv[j] = *(const float4*)(&Z[(ngrp + 16 * j) * ZS + k4 * 4]);
        #pragma unroll
        for (int i = 0; i < 4; i++)
            wv[i] = *(const float4*)(&Wl[(k4 * 4 + i) * HID + c0]);
        #pragma unroll
        for (int j = 0; j < 4; j++) {
            const float z0 = zv[j].x, z1 = zv[j].y, z2 = zv[j].z, z3 = zv[j].w;
            acc1[j][0] += z0 * wv[0].x + z1 * wv[1].x + z2 * wv[2].x + z3 * wv[3].x;
            acc1[j][1] += z0 * wv[0].y + z1 * wv[1].y + z2 * wv[2].y + z3 * wv[3].y;
            acc1[j][2] += z0 * wv[0].z + z1 * wv[1].z + z2 * wv[2].z + z3 * wv[3].z;
            acc1[j][3] += z0 * wv[0].w + z1 * wv[1].w + z2 * wv[2].w + z3 * wv[3].w;
        }
    }
    __syncthreads();   // GEMM1 reads of Z/Wl done

    // t1 = relu(bn1(.)) back into Z; stage W2
    #pragma unroll
    for (int j = 0; j < 4; j++) {
        const int n = ngrp + 16 * j;
        float4 o;
        o.x = fmaxf(acc1[j][0] * s1c[0] + c1c[0], 0.f);
        o.y = fmaxf(acc1[j][1] * s1c[1] + c1c[1], 0.f);
        o.z = fmaxf(acc1[j][2] * s1c[2] + c1c[2], 0.f);
        o.w = fmaxf(acc1[j][3] * s1c[3] + c1c[3], 0.f);
        *(float4*)(&Z[n * ZS + c0]) = o;
    }
    #pragma unroll
    for (int i = 0; i < 4; i++) {
        const int idx = t + i * 256;
        const int k = idx >> 4, k4 = idx & 15;
        *(float4*)(&Wl[k * HID + k4 * 4]) = *(const float4*)(w2 + (size_t)k * HID + k4 * 4);
    }
    __syncthreads();

    // GEMM2
    float acc2[4][4] = {};
    #pragma unroll
    for (int k4 = 0; k4 < 16; k4++) {
        float4 zv[4], wv[4];
        #pragma unroll
        for (int j = 0; j < 4; j++)
            zv[j] = *(const float4*)(&Z[(ngrp + 16 * j) * ZS + k4 * 4]);
        #pragma unroll
        for (int i = 0; i < 4; i++)
            wv[i] = *(const float4*)(&Wl[(k4 * 4 + i) * HID + c0]);
        #pragma unroll
        for (int j = 0; j < 4; j++) {
            const float z0 = zv[j].x, z1 = zv[j].y, z2 = zv[j].z, z3 = zv[j].w;
            acc2[j][0] += z0 * wv[0].x + z1 * wv[1].x + z2 * wv[2].x + z3 * wv[3].x;
            acc2[j][1] += z0 * wv[0].y + z1 * wv[1].y + z2 * wv[2].y + z3 * wv[3].y;
            acc2[j][2] += z0 * wv[0].z + z1 * wv[1].z + z2 * wv[2].z + z3 * wv[3].z;
            acc2[j][3] += z0 * wv[0].w + z1 * wv[1].w + z2 * wv[2].w + z3 * wv[3].w;
        }
    }

    #pragma unroll
    for (int j = 0; j < 4; j++) {
        const int n = base + ngrp + 16 * j;
        float4 o;
        o.x = fmaxf(acc2[j][0] * s2c[0] + c2c[0], 0.f);
        o.y = fmaxf(acc2[j][1] * s2c[1] + c2c[1], 0.f);
        o.z = fmaxf(acc2[j][2] * s2c[2] + c2c[2], 0.f);
        o.w = fmaxf(acc2[j][3] * s2c[3] + c2c[3], 0.f);
        *(float4*)(hout + (size_t)n * HID + c0) = o;
    }
}

// ===========================================================================
// Pool: batch sorted; register run-accumulation, one atomic per transition.
// ===========================================================================
__global__ __launch_bounds__(256) void pool_kernel(
    const float* __restrict__ h, const int* __restrict__ batch,
    float* __restrict__ pooled, float* __restrict__ cnt)
{
    const int CHUNK = 256;
    const int wid = (blockIdx.x * 256 + threadIdx.x) >> 6;
    const int lane = threadIdx.x & 63;
    const int start = wid * CHUNK;
    if (start >= N_NODES) return;
    const int end = (start + CHUNK < N_NODES) ? (start + CHUNK) : N_NODES;
    int cur = batch[start];
    float acc = 0.f, c = 0.f;
    for (int n = start; n < end; n++) {
        const int g = batch[n];
        if (g != cur) {
            atomicAdd(&pooled[(size_t)cur * HID + lane], acc);
            if (lane == 0) atomicAdd(&cnt[cur], c);
            cur = g; acc = 0.f; c = 0.f;
        }
        acc += h[(size_t)n * HID + lane];
        c += 1.f;
    }
    atomicAdd(&pooled[(size_t)cur * HID + lane], acc);
    if (lane == 0) atomicAdd(&cnt[cur], c);
}

// ===========================================================================
// Classifier
// ===========================================================================
__global__ __launch_bounds__(64) void cls_kernel(
    const float* __restrict__ pooled, const float* __restrict__ cnt,
    const float* __restrict__ w1, const float* __restrict__ b1,
    const float* __restrict__ w2, const float* __restrict__ b2,
    float* __restrict__ out)
{
    const int g = blockIdx.x;
    const int lane = threadIdx.x;
    const float c = cnt[g];
    const float p = pooled[(size_t)g * HID + lane] / fmaxf(c, 1.f);
    float acc = (lane < 32) ? b1[lane] : 0.f;
    #pragma unroll
    for (int k = 0; k < 64; k++) {
        const float pk = __shfl(p, k, 64);
        if (lane < 32) acc += pk * w1[k * 32 + lane];
    }
    const float hmid = fmaxf(acc, 0.f);
    float acc2 = (lane < NCLS) ? b2[lane] : 0.f;
    #pragma unroll
    for (int k = 0; k < 32; k++) {
        const float hk = __shfl(hmid, k, 64);
        if (lane < NCLS) acc2 += hk * w2[k * NCLS + lane];
    }
    if (lane < NCLS) out[(size_t)g * NCLS + lane] = acc2;
}

// ===========================================================================
extern "C" void kernel_launch(void* const* d_in, const int* in_sizes, int n_in,
                              void* d_out, int out_size, void* d_ws, size_t ws_size,
                              hipStream_t stream) {
    const float* x     = (const float*)d_in[0];
    const int*   ei    = (const int*)d_in[1];            // [2,E]
    const int*   batch = (const int*)d_in[2];
    const float* emb_w = (const float*)d_in[3];
    const float* emb_b = (const float*)d_in[4];
    const float* ibn_g = (const float*)d_in[5];
    const float* ibn_b = (const float*)d_in[6];
    const float* ibn_m = (const float*)d_in[7];
    const float* ibn_v = (const float*)d_in[8];
    const float* fc1_w = (const float*)d_in[9];
    const float* fc1_b = (const float*)d_in[10];
    const float* mbn_g = (const float*)d_in[11];
    const float* mbn_b = (const float*)d_in[12];
    const float* mbn_m = (const float*)d_in[13];
    const float* mbn_v = (const float*)d_in[14];
    const float* fc2_w = (const float*)d_in[15];
    const float* fc2_b = (const float*)d_in[16];
    const float* obn_g = (const float*)d_in[17];
    const float* obn_b = (const float*)d_in[18];
    const float* obn_m = (const float*)d_in[19];
    const float* obn_v = (const float*)d_in[20];
    const float* cls1w = (const float*)d_in[21];
    const float* cls1b = (const float*)d_in[22];
    const float* cls2w = (const float*)d_in[23];
    const float* cls2b = (const float*)d_in[24];

    float* h0     = (float*)d_ws;                        // 12.8M floats
    float* h1     = h0 + (size_t)N_NODES * HID;          // 12.8M floats
    float* pooled = h1 + (size_t)N_NODES * HID;          // 65536
    float* cnt    = pooled + NGRAPH * HID;               // 1024
    int*   deg    = (int*)(cnt + NGRAPH);                // 200000 (reused as cursor)
    int*   offs   = deg + N_NODES;                       // 200001
    int*   bsum   = offs + (N_NODES + 1);                // 196
    int*   boff   = bsum + NBLK_SCAN;                    // 196
    int*   csr    = boff + NBLK_SCAN;                    // 1.2M

    const int* src = ei;
    const int* dst = ei + N_EDGES;

    // ---- CSR build (once, reused by all 3 layers) ----
    hipMemsetAsync(deg, 0, N_NODES * sizeof(int), stream);
    hipMemsetAsync(pooled, 0, (size_t)(NGRAPH * HID + NGRAPH) * sizeof(float), stream);
    hist_kernel<<<(N_EDGES + 255) / 256, 256, 0, stream>>>(dst, deg);
    scan_sum_kernel<<<NBLK_SCAN, 256, 0, stream>>>(deg, bsum);
    scan_block_kernel<<<1, 256, 0, stream>>>(bsum, boff, offs);
    scan_scatter_kernel<<<NBLK_SCAN, 256, 0, stream>>>(deg, boff, offs);
    hipMemcpyAsync(deg, offs, N_NODES * sizeof(int), hipMemcpyDeviceToDevice, stream);
    bucket_kernel<<<(N_EDGES + 255) / 256, 256, 0, stream>>>(src, dst, deg, csr);

    // ---- network ----
    const int gemm_blocks = N_NODES / TILE_N;   // 3125
    embed_kernel<<<gemm_blocks, 256, 0, stream>>>(x, emb_w, emb_b,
                                                  ibn_g, ibn_b, ibn_m, ibn_v, h0);

    const float* hin = h0;
    float* hout = h1;
    for (int i = 0; i < 3; i++) {
        agg_mlp_kernel<<<gemm_blocks, 256, 0, stream>>>(
            hin, hout, offs, csr,
            fc1_w + i * HID * HID, fc1_b + i * HID,
            mbn_g + i * HID, mbn_b + i * HID, mbn_m + i * HID, mbn_v + i * HID,
            fc2_w + i * HID * HID, fc2_b + i * HID,
            obn_g + i * HID, obn_b + i * HID, obn_m + i * HID, obn_v + i * HID);
        const float* tmp = hin; hin = hout; hout = (float*)tmp;
    }
    // after 3 layers: result in h1 (h0->h1->h0->h1)

    const int pool_waves = (N_NODES + 255) / 256;
    pool_kernel<<<(pool_waves + 3) / 4, 256, 0, stream>>>(h1, batch, pooled, cnt);

    cls_kernel<<<NGRAPH, 64, 0, stream>>>(pooled, cnt, cls1w, cls1b, cls2w, cls2b,
                                          (float*)d_out);
}

// Round 7
// 808.716 us; speedup vs baseline: 2.3401x; 1.4038x over previous
//
#include <hip/hip_runtime.h>
#include <hip/hip_bf16.h>

#define N_NODES 200000
#define N_EDGES 1200000
#define IN_DIM  128
#define HID     64
#define NGRAPH  1024
#define NCLS    6
#define BN_EPS  1e-5f

#define TILE_N   64          // nodes per GEMM block
#define XSTRIDE  132         // embed x-tile row stride (floats), bank-safe
#define ZS       68          // mlp z-tile row stride (floats), 16B-aligned, bank-safe
#define ECAP     1024        // LDS edge-index cache (mean segment = 384, 32 sd below cap)

#define SCAN_CHUNK 1024
#define NBLK_SCAN ((N_NODES + SCAN_CHUNK - 1) / SCAN_CHUNK)   // 196

// ===========================================================================
// CSR build: deg histogram -> 3-step scan -> bucket scatter of src ids.
// ===========================================================================
__global__ __launch_bounds__(256) void hist_kernel(
    const int* __restrict__ dst, int* __restrict__ deg)
{
    const int e = blockIdx.x * 256 + threadIdx.x;
    if (e < N_EDGES) atomicAdd(&deg[dst[e]], 1);
}

__global__ __launch_bounds__(256) void scan_sum_kernel(
    const int* __restrict__ deg, int* __restrict__ bsum)
{
    __shared__ int sd[256];
    const int b = blockIdx.x, t = threadIdx.x;
    const int base = b * SCAN_CHUNK;
    int s = 0;
    #pragma unroll
    for (int i = 0; i < SCAN_CHUNK / 256; i++) {
        const int idx = base + t + i * 256;
        s += (idx < N_NODES) ? deg[idx] : 0;
    }
    sd[t] = s; __syncthreads();
    for (int off = 128; off > 0; off >>= 1) {
        if (t < off) sd[t] += sd[t + off];
        __syncthreads();
    }
    if (t == 0) bsum[b] = sd[0];
}

__global__ __launch_bounds__(256) void scan_block_kernel(
    const int* __restrict__ bsum, int* __restrict__ boff, int* __restrict__ offs)
{
    __shared__ int sd[256];
    const int t = threadIdx.x;
    const int v = (t < NBLK_SCAN) ? bsum[t] : 0;
    sd[t] = v; __syncthreads();
    for (int off = 1; off < 256; off <<= 1) {
        const int u = (t >= off) ? sd[t - off] : 0;
        __syncthreads();
        sd[t] += u;
        __syncthreads();
    }
    if (t < NBLK_SCAN) boff[t] = sd[t] - v;   // exclusive
    if (t == 0) offs[N_NODES] = N_EDGES;
}

__global__ __launch_bounds__(256) void scan_scatter_kernel(
    const int* __restrict__ deg, const int* __restrict__ boff, int* __restrict__ offs)
{
    __shared__ int sd[256];
    const int b = blockIdx.x, t = threadIdx.x;
    const int base = b * SCAN_CHUNK + t * 4;
    int d0 = 0, d1 = 0, d2 = 0, d3 = 0;
    if (base + 0 < N_NODES) d0 = deg[base + 0];
    if (base + 1 < N_NODES) d1 = deg[base + 1];
    if (base + 2 < N_NODES) d2 = deg[base + 2];
    if (base + 3 < N_NODES) d3 = deg[base + 3];
    const int ts = d0 + d1 + d2 + d3;
    sd[t] = ts; __syncthreads();
    for (int off = 1; off < 256; off <<= 1) {
        const int u = (t >= off) ? sd[t - off] : 0;
        __syncthreads();
        sd[t] += u;
        __syncthreads();
    }
    const int excl = sd[t] - ts + boff[b];
    if (base + 0 < N_NODES) offs[base + 0] = excl;
    if (base + 1 < N_NODES) offs[base + 1] = excl + d0;
    if (base + 2 < N_NODES) offs[base + 2] = excl + d0 + d1;
    if (base + 3 < N_NODES) offs[base + 3] = excl + d0 + d1 + d2;
}

__global__ __launch_bounds__(256) void bucket_kernel(
    const int* __restrict__ src, const int* __restrict__ dst,
    int* __restrict__ cursor, int* __restrict__ csr_src)
{
    const int e = blockIdx.x * 256 + threadIdx.x;
    if (e < N_EDGES) {
        const int pos = atomicAdd(&cursor[dst[e]], 1);
        csr_src[pos] = src[e];
    }
}

// ===========================================================================
// Embed: h0 = relu(bn(x @ W + b)). Register-blocked LDS GEMM, K=128 in halves.
// ===========================================================================
__global__ __launch_bounds__(256) void embed_kernel(
    const float* __restrict__ x,      // [N,128]
    const float* __restrict__ w,      // [128,64]
    const float* __restrict__ bias,
    const float* __restrict__ bn_g, const float* __restrict__ bn_b,
    const float* __restrict__ bn_m, const float* __restrict__ bn_v,
    float* __restrict__ h)            // [N,64]
{
    __shared__ float Z[TILE_N * XSTRIDE];   // 33792 B
    __shared__ float Wl[64 * HID];          // 16384 B
    const int t = threadIdx.x;
    const int cgrp = t & 15, ngrp = t >> 4;
    const int c0 = cgrp * 4;
    const int base = blockIdx.x * TILE_N;

    #pragma unroll
    for (int i = 0; i < 8; i++) {
        const int idx = t + i * 256;            // 0..2047
        const int n = idx >> 5, k4 = idx & 31;
        *(float4*)(&Z[n * XSTRIDE + k4 * 4]) =
            *(const float4*)(x + (size_t)(base + n) * IN_DIM + k4 * 4);
    }

    float scale[4], shift[4];
    #pragma unroll
    for (int cc = 0; cc < 4; cc++) {
        const int c = c0 + cc;
        const float s = bn_g[c] * rsqrtf(bn_v[c] + BN_EPS);
        scale[cc] = s;
        shift[cc] = bias[c] * s + bn_b[c] - bn_m[c] * s;
    }

    float acc[4][4] = {};
    for (int kh = 0; kh < 2; kh++) {
        __syncthreads();
        #pragma unroll
        for (int i = 0; i < 4; i++) {
            const int idx = t + i * 256;
            const int k = idx >> 4, k4 = idx & 15;
            *(float4*)(&Wl[k * HID + k4 * 4]) =
                *(const float4*)(w + (size_t)(kh * 64 + k) * HID + k4 * 4);
        }
        __syncthreads();

        #pragma unroll
        for (int k4 = 0; k4 < 16; k4++) {
            float4 zv[4], wv[4];
            #pragma unroll
            for (int j = 0; j < 4; j++)
                zv[j] = *(const float4*)(&Z[(ngrp + 16 * j) * XSTRIDE + (kh * 16 + k4) * 4]);
            #pragma unroll
            for (int i = 0; i < 4; i++)
                wv[i] = *(const float4*)(&Wl[(k4 * 4 + i) * HID + c0]);
            #pragma unroll
            for (int j = 0; j < 4; j++) {
                const float z0 = zv[j].x, z1 = zv[j].y, z2 = zv[j].z, z3 = zv[j].w;
                acc[j][0] += z0 * wv[0].x + z1 * wv[1].x + z2 * wv[2].x + z3 * wv[3].x;
                acc[j][1] += z0 * wv[0].y + z1 * wv[1].y + z2 * wv[2].y + z3 * wv[3].y;
                acc[j][2] += z0 * wv[0].z + z1 * wv[1].z + z2 * wv[2].z + z3 * wv[3].z;
                acc[j][3] += z0 * wv[0].w + z1 * wv[1].w + z2 * wv[2].w + z3 * wv[3].w;
            }
        }
    }

    #pragma unroll
    for (int j = 0; j < 4; j++) {
        const int n = base + ngrp + 16 * j;
        float4 o;
        o.x = fmaxf(acc[j][0] * scale[0] + shift[0], 0.f);
        o.y = fmaxf(acc[j][1] * scale[1] + shift[1], 0.f);
        o.z = fmaxf(acc[j][2] * scale[2] + shift[2], 0.f);
        o.w = fmaxf(acc[j][3] * scale[3] + shift[3], 0.f);
        *(float4*)(h + (size_t)n * HID + c0) = o;
    }
}

// ===========================================================================
// Fused GIN layer. Gather: 4 nodes/wave per pass (16-lane group per node,
// cq = float4 of channels), 4-deep branch-free unroll (tail indices clamped,
// invalid contributions zeroed by multiply) -> 4 independent row loads in
// flight per group, no exec-mask bookkeeping. Tile's contiguous CSR segment
// staged in LDS so index fetches are ~60cyc broadcasts, not global loads.
// Then two register-blocked GEMMs. No atomics anywhere.
// ===========================================================================
__global__ __launch_bounds__(256) void agg_mlp_kernel(
    const float* __restrict__ hin, float* __restrict__ hout,
    const int* __restrict__ offs, const int* __restrict__ csr,
    const float* __restrict__ w1, const float* __restrict__ b1,
    const float* __restrict__ g1, const float* __restrict__ bb1,
    const float* __restrict__ m1, const float* __restrict__ v1,
    const float* __restrict__ w2, const float* __restrict__ b2,
    const float* __restrict__ g2, const float* __restrict__ bb2,
    const float* __restrict__ m2, const float* __restrict__ v2)
{
    __shared__ float Z[TILE_N * ZS];        // 17408 B
    __shared__ float Wl[HID * HID];         // 16384 B
    __shared__ int   OF[TILE_N + 1];        // 260 B
    __shared__ int   EIDX[ECAP];            // 4096 B   (total ~38 KB -> 4 blocks/CU)
    const int t = threadIdx.x;
    const int lane = t & 63, w = t >> 6;
    const int sub = lane >> 4, cq = lane & 15;
    const int cgrp = t & 15, ngrp = t >> 4;
    const int c0 = cgrp * 4;
    const int base = blockIdx.x * TILE_N;

    // stage W1
    #pragma unroll
    for (int i = 0; i < 4; i++) {
        const int idx = t + i * 256;
        const int k = idx >> 4, k4 = idx & 15;
        *(float4*)(&Wl[k * HID + k4 * 4]) = *(const float4*)(w1 + (size_t)k * HID + k4 * 4);
    }
    // stage CSR offsets + edge-index segment for this tile (coalesced)
    if (t <= TILE_N) OF[t] = offs[base + t];
    const int segStart = offs[base];
    const int segEnd   = offs[base + TILE_N];
    for (int i = t; i < segEnd - segStart; i += 256)
        if (i < ECAP) EIDX[i] = csr[segStart + i];
    __syncthreads();

    // gather: 4 passes x (4 waves x 4 groups) = 64 nodes
    const float* __restrict__ hc = hin + cq * 4;   // this lane's channel quad
    #pragma unroll
    for (int p = 0; p < 4; p++) {
        const int nl = w * 16 + p * 4 + sub;
        const int e0 = OF[nl], e1 = OF[nl + 1];
        float4 acc = *(const float4*)(hin + (size_t)(base + nl) * HID + cq * 4); // self
        if (e0 < e1) {
            const int e1m = e1 - 1;
            for (int e = e0; e < e1; e += 4) {
                // clamped edge ids: always valid, duplicates masked by m*
                const int ea = e;
                const int eb = (e + 1 < e1) ? e + 1 : e1m;
                const int ec = (e + 2 < e1) ? e + 2 : e1m;
                const int ed = (e + 3 < e1) ? e + 3 : e1m;
                const int la = ea - segStart, lb = eb - segStart;
                const int lc = ec - segStart, ld = ed - segStart;
                const int s0 = (la < ECAP) ? EIDX[la] : csr[ea];
                const int s1 = (lb < ECAP) ? EIDX[lb] : csr[eb];
                const int s2 = (lc < ECAP) ? EIDX[lc] : csr[ec];
                const int s3 = (ld < ECAP) ? EIDX[ld] : csr[ed];
                const float4 v0 = *(const float4*)(hc + (size_t)s0 * HID);
                const float4 v1 = *(const float4*)(hc + (size_t)s1 * HID);
                const float4 v2 = *(const float4*)(hc + (size_t)s2 * HID);
                const float4 v3 = *(const float4*)(hc + (size_t)s3 * HID);
                const float m1 = (e + 1 < e1) ? 1.f : 0.f;
                const float m2 = (e + 2 < e1) ? 1.f : 0.f;
                const float m3 = (e + 3 < e1) ? 1.f : 0.f;
                acc.x += v0.x + m1 * v1.x + m2 * v2.x + m3 * v3.x;
                acc.y += v0.y + m1 * v1.y + m2 * v2.y + m3 * v3.y;
                acc.z += v0.z + m1 * v1.z + m2 * v2.z + m3 * v3.z;
                acc.w += v0.w + m1 * v1.w + m2 * v2.w + m3 * v3.w;
            }
        }
        *(float4*)(&Z[nl * ZS + cq * 4]) = acc;
    }

    float s1c[4], c1c[4], s2c[4], c2c[4];
    #pragma unroll
    for (int cc = 0; cc < 4; cc++) {
        const int c = c0 + cc;
        const float sa = g1[c] * rsqrtf(v1[c] + BN_EPS);
        s1c[cc] = sa; c1c[cc] = b1[c] * sa + bb1[c] - m1[c] * sa;
        const float sb = g2[c] * rsqrtf(v2[c] + BN_EPS);
        s2c[cc] = sb; c2c[cc] = b2[c] * sb + bb2[c] - m2[c] * sb;
    }
    __syncthreads();   // Z complete

    // GEMM1
    float acc1[4][4] = {};
    #pragma unroll
    for (int k4 = 0; k4 < 16; k4++) {
        float4 zv[4], wv[4];
        #pragma unroll
        for (int j = 0; j < 4; j++)
            zv[j] = *(const float4*)(&Z[(ngrp + 16 * j) * ZS + k4 * 4]);
        #pragma unroll
        for (int i = 0; i < 4; i++)
            wv[i] = *(const float4*)(&Wl[(k4 * 4 + i) * HID + c0]);
        #pragma unroll
        for (int j = 0; j < 4; j++) {
            const float z0 = zv[j].x, z1 = zv[j].y, z2 = zv[j].z, z3 = zv[j].w;
            acc1[j][0] += z0 * wv[0].x + z1 * wv[1].x + z2 * wv[2].x + z3 * wv[3].x;
            acc1[j][1] += z0 * wv[0].y + z1 * wv[1].y + z2 * wv[2].y + z3 * wv[3].y;
            acc1[j][2] += z0 * wv[0].z + z1 * wv[1].z + z2 * wv[2].z + z3 * wv[3].z;
            acc1[j][3] += z0 * wv[0].w + z1 * wv[1].w + z2 * wv[2].w + z3 * wv[3].w;
        }
    }
    __syncthreads();   // GEMM1 reads of Z/Wl done

    // t1 = relu(bn1(.)) back into Z; stage W2
    #pragma unroll
    for (int j = 0; j < 4; j++) {
        const int n = ngrp + 16 * j;
        float4 o;
        o.x = fmaxf(acc1[j][0] * s1c[0] + c1c[0], 0.f);
        o.y = fmaxf(acc1[j][1] * s1c[1] + c1c[1], 0.f);
        o.z = fmaxf(acc1[j][2] * s1c[2] + c1c[2], 0.f);
        o.w = fmaxf(acc1[j][3] * s1c[3] + c1c[3], 0.f);
        *(float4*)(&Z[n * ZS + c0]) = o;
    }
    #pragma unroll
    for (int i = 0; i < 4; i++) {
        const int idx = t + i * 256;
        const int k = idx >> 4, k4 = idx & 15;
        *(float4*)(&Wl[k * HID + k4 * 4]) = *(const float4*)(w2 + (size_t)k * HID + k4 * 4);
    }
    __syncthreads();

    // GEMM2
    float acc2[4][4] = {};
    #pragma unroll
    for (int k4 = 0; k4 < 16; k4++) {
        float4 zv[4], wv[4];
        #pragma unroll
        for (int j = 0; j < 4; j++)
            zv[j] = *(const float4*)(&Z[(ngrp + 16 * j) * ZS + k4 * 4]);
        #pragma unroll
        for (int i = 0; i < 4; i++)
            wv[i] = *(const float4*)(&Wl[(k4 * 4 + i) * HID + c0]);
        #pragma unroll
        for (int j = 0; j < 4; j++) {
            const float z0 = zv[j].x, z1 = zv[j].y, z2 = zv[j].z, z3 = zv[j].w;
            acc2[j][0] += z0 * wv[0].x + z1 * wv[1].x + z2 * wv[2].x + z3 * wv[3].x;
            acc2[j][1] += z0 * wv[0].y + z1 * wv[1].y + z2 * wv[2].y + z3 * wv[3].y;
            acc2[j][2] += z0 * wv[0].z + z1 * wv[1].z + z2 * wv[2].z + z3 * wv[3].z;
            acc2[j][3] += z0 * wv[0].w + z1 * wv[1].w + z2 * wv[2].w + z3 * wv[3].w;
        }
    }

    #pragma unroll
    for (int j = 0; j < 4; j++) {
        const int n = base + ngrp + 16 * j;
        float4 o;
        o.x = fmaxf(acc2[j][0] * s2c[0] + c2c[0], 0.f);
        o.y = fmaxf(acc2[j][1] * s2c[1] + c2c[1], 0.f);
        o.z = fmaxf(acc2[j][2] * s2c[2] + c2c[2], 0.f);
        o.w = fmaxf(acc2[j][3] * s2c[3] + c2c[3], 0.f);
        *(float4*)(hout + (size_t)n * HID + c0) = o;
    }
}

// ===========================================================================
// Pool: batch sorted; register run-accumulation, one atomic per transition.
// ===========================================================================
__global__ __launch_bounds__(256) void pool_kernel(
    const float* __restrict__ h, const int* __restrict__ batch,
    float* __restrict__ pooled, float* __restrict__ cnt)
{
    const int CHUNK = 256;
    const int wid = (blockIdx.x * 256 + threadIdx.x) >> 6;
    const int lane = threadIdx.x & 63;
    const int start = wid * CHUNK;
    if (start >= N_NODES) return;
    const int end = (start + CHUNK < N_NODES) ? (start + CHUNK) : N_NODES;
    int cur = batch[start];
    float acc = 0.f, c = 0.f;
    for (int n = start; n < end; n++) {
        const int g = batch[n];
        if (g != cur) {
            atomicAdd(&pooled[(size_t)cur * HID + lane], acc);
            if (lane == 0) atomicAdd(&cnt[cur], c);
            cur = g; acc = 0.f; c = 0.f;
        }
        acc += h[(size_t)n * HID + lane];
        c += 1.f;
    }
    atomicAdd(&pooled[(size_t)cur * HID + lane], acc);
    if (lane == 0) atomicAdd(&cnt[cur], c);
}

// ===========================================================================
// Classifier
// ===========================================================================
__global__ __launch_bounds__(64) void cls_kernel(
    const float* __restrict__ pooled, const float* __restrict__ cnt,
    const float* __restrict__ w1, const float* __restrict__ b1,
    const float* __restrict__ w2, const float* __restrict__ b2,
    float* __restrict__ out)
{
    const int g = blockIdx.x;
    const int lane = threadIdx.x;
    const float c = cnt[g];
    const float p = pooled[(size_t)g * HID + lane] / fmaxf(c, 1.f);
    float acc = (lane < 32) ? b1[lane] : 0.f;
    #pragma unroll
    for (int k = 0; k < 64; k++) {
        const float pk = __shfl(p, k, 64);
        if (lane < 32) acc += pk * w1[k * 32 + lane];
    }
    const float hmid = fmaxf(acc, 0.f);
    float acc2 = (lane < NCLS) ? b2[lane] : 0.f;
    #pragma unroll
    for (int k = 0; k < 32; k++) {
        const float hk = __shfl(hmid, k, 64);
        if (lane < NCLS) acc2 += hk * w2[k * NCLS + lane];
    }
    if (lane < NCLS) out[(size_t)g * NCLS + lane] = acc2;
}

// ===========================================================================
extern "C" void kernel_launch(void* const* d_in, const int* in_sizes, int n_in,
                              void* d_out, int out_size, void* d_ws, size_t ws_size,
                              hipStream_t stream) {
    const float* x     = (const float*)d_in[0];
    const int*   ei    = (const int*)d_in[1];            // [2,E]
    const int*   batch = (const int*)d_in[2];
    const float* emb_w = (const float*)d_in[3];
    const float* emb_b = (const float*)d_in[4];
    const float* ibn_g = (const float*)d_in[5];
    const float* ibn_b = (const float*)d_in[6];
    const float* ibn_m = (const float*)d_in[7];
    const float* ibn_v = (const float*)d_in[8];
    const float* fc1_w = (const float*)d_in[9];
    const float* fc1_b = (const float*)d_in[10];
    const float* mbn_g = (const float*)d_in[11];
    const float* mbn_b = (const float*)d_in[12];
    const float* mbn_m = (const float*)d_in[13];
    const float* mbn_v = (const float*)d_in[14];
    const float* fc2_w = (const float*)d_in[15];
    const float* fc2_b = (const float*)d_in[16];
    const float* obn_g = (const float*)d_in[17];
    const float* obn_b = (const float*)d_in[18];
    const float* obn_m = (const float*)d_in[19];
    const float* obn_v = (const float*)d_in[20];
    const float* cls1w = (const float*)d_in[21];
    const float* cls1b = (const float*)d_in[22];
    const float* cls2w = (const float*)d_in[23];
    const float* cls2b = (const float*)d_in[24];

    float* h0     = (float*)d_ws;                        // 12.8M floats
    float* h1     = h0 + (size_t)N_NODES * HID;          // 12.8M floats
    float* pooled = h1 + (size_t)N_NODES * HID;          // 65536
    float* cnt    = pooled + NGRAPH * HID;               // 1024
    int*   deg    = (int*)(cnt + NGRAPH);                // 200000 (reused as cursor)
    int*   offs   = deg + N_NODES;                       // 200001
    int*   bsum   = offs + (N_NODES + 1);                // 196
    int*   boff   = bsum + NBLK_SCAN;                    // 196
    int*   csr    = boff + NBLK_SCAN;                    // 1.2M

    const int* src = ei;
    const int* dst = ei + N_EDGES;

    // ---- CSR build (once, reused by all 3 layers) ----
    hipMemsetAsync(deg, 0, N_NODES * sizeof(int), stream);
    hipMemsetAsync(pooled, 0, (size_t)(NGRAPH * HID + NGRAPH) * sizeof(float), stream);
    hist_kernel<<<(N_EDGES + 255) / 256, 256, 0, stream>>>(dst, deg);
    scan_sum_kernel<<<NBLK_SCAN, 256, 0, stream>>>(deg, bsum);
    scan_block_kernel<<<1, 256, 0, stream>>>(bsum, boff, offs);
    scan_scatter_kernel<<<NBLK_SCAN, 256, 0, stream>>>(deg, boff, offs);
    hipMemcpyAsync(deg, offs, N_NODES * sizeof(int), hipMemcpyDeviceToDevice, stream);
    bucket_kernel<<<(N_EDGES + 255) / 256, 256, 0, stream>>>(src, dst, deg, csr);

    // ---- network ----
    const int gemm_blocks = N_NODES / TILE_N;   // 3125
    embed_kernel<<<gemm_blocks, 256, 0, stream>>>(x, emb_w, emb_b,
                                                  ibn_g, ibn_b, ibn_m, ibn_v, h0);

    const float* hin = h0;
    float* hout = h1;
    for (int i = 0; i < 3; i++) {
        agg_mlp_kernel<<<gemm_blocks, 256, 0, stream>>>(
            hin, hout, offs, csr,
            fc1_w + i * HID * HID, fc1_b + i * HID,
            mbn_g + i * HID, mbn_b + i * HID, mbn_m + i * HID, mbn_v + i * HID,
            fc2_w + i * HID * HID, fc2_b + i * HID,
            obn_g + i * HID, obn_b + i * HID, obn_m + i * HID, obn_v + i * HID);
        const float* tmp = hin; hin = hout; hout = (float*)tmp;
    }
    // after 3 layers: result in h1 (h0->h1->h0->h1)

    const int pool_waves = (N_NODES + 255) / 256;
    pool_kernel<<<(pool_waves + 3) / 4, 256, 0, stream>>>(h1, batch, pooled, cnt);

    cls_kernel<<<NGRAPH, 64, 0, stream>>>(pooled, cnt, cls1w, cls1b, cls2w, cls2b,
                                          (float*)d_out);
}

// Round 8
// 698.032 us; speedup vs baseline: 2.7112x; 1.1586x over previous
//
#include <hip/hip_runtime.h>
#include <hip/hip_bf16.h>

#define N_NODES 200000
#define N_EDGES 1200000
#define IN_DIM  128
#define HID     64
#define NGRAPH  1024
#define NCLS    6
#define BN_EPS  1e-5f

#define TILE_N   64
#define ZS       68          // Ztmp row stride (floats); 272B = 17 banks shift, 2-way max
#define ECAP     1024

#define SCAN_CHUNK 1024
#define NBLK_SCAN ((N_NODES + SCAN_CHUNK - 1) / SCAN_CHUNK)   // 196

typedef short bf16x8 __attribute__((ext_vector_type(8)));
typedef float f32x4  __attribute__((ext_vector_type(4)));
#define MFMA16(a,b,c) __builtin_amdgcn_mfma_f32_16x16x32_bf16((a),(b),(c),0,0,0)

__device__ __forceinline__ unsigned short f2bf(float f) {
    union { __hip_bfloat16 h; unsigned short u; } v; v.h = __float2bfloat16(f); return v.u;
}
__device__ __forceinline__ float bfbits2f(unsigned short u) {
    union { unsigned int i; float f; } v; v.i = ((unsigned int)u) << 16; return v.f;
}
// float4 -> (hi bf16x4, lo bf16x4) packed as uint2 each
__device__ __forceinline__ void cvt4(const float4& x, uint2& hi, uint2& lo) {
    const unsigned short h0 = f2bf(x.x), h1 = f2bf(x.y), h2 = f2bf(x.z), h3 = f2bf(x.w);
    hi.x = (unsigned)h0 | ((unsigned)h1 << 16);
    hi.y = (unsigned)h2 | ((unsigned)h3 << 16);
    const unsigned short l0 = f2bf(x.x - bfbits2f(h0)), l1 = f2bf(x.y - bfbits2f(h1));
    const unsigned short l2 = f2bf(x.z - bfbits2f(h2)), l3 = f2bf(x.w - bfbits2f(h3));
    lo.x = (unsigned)l0 | ((unsigned)l1 << 16);
    lo.y = (unsigned)l2 | ((unsigned)l3 << 16);
}

// ===========================================================================
// Weight prep: pack W into MFMA B-fragment order (bf16 hi/lo planes).
// B-frag: lane l holds B[k = (l>>4)*8+j][n = l&15], j=0..7 contiguous.
// ===========================================================================
__global__ __launch_bounds__(256) void prep_emb_kernel(
    const float* __restrict__ w, unsigned short* __restrict__ wpe)   // [128][64] -> 16384
{
    const int idx = blockIdx.x * 256 + threadIdx.x;      // [ct2][s2][p1][l6][j3]
    if (idx >= 16384) return;
    const int j = idx & 7, l = (idx >> 3) & 63;
    const int plane = (idx >> 9) & 1, s = (idx >> 10) & 3, ct = (idx >> 12) & 3;
    const int n = ct * 16 + (l & 15);
    const int k = s * 32 + (l >> 4) * 8 + j;
    const float f = w[k * 64 + n];
    const unsigned short hb = f2bf(f);
    wpe[idx] = plane ? f2bf(f - bfbits2f(hb)) : hb;
}

__global__ __launch_bounds__(256) void prep_fc_kernel(
    const float* __restrict__ fc1, const float* __restrict__ fc2,
    unsigned short* __restrict__ wpf)                    // 3*2*8192 = 49152
{
    const int idx = blockIdx.x * 256 + threadIdx.x;      // [layer][g][ct2][s1][p1][l6][j3]
    if (idx >= 49152) return;
    const int j = idx & 7, l = (idx >> 3) & 63;
    const int plane = (idx >> 9) & 1, s = (idx >> 10) & 1, ct = (idx >> 11) & 3;
    const int g = (idx >> 13) & 1, layer = idx >> 14;
    const int n = ct * 16 + (l & 15);
    const int k = s * 32 + (l >> 4) * 8 + j;
    const float* W = g ? fc2 : fc1;
    const float f = W[(layer * 64 + k) * 64 + n];
    const unsigned short hb = f2bf(f);
    wpf[idx] = plane ? f2bf(f - bfbits2f(hb)) : hb;
}

// ===========================================================================
// CSR build (unchanged)
// ===========================================================================
__global__ __launch_bounds__(256) void hist_kernel(
    const int* __restrict__ dst, int* __restrict__ deg)
{
    const int e = blockIdx.x * 256 + threadIdx.x;
    if (e < N_EDGES) atomicAdd(&deg[dst[e]], 1);
}

__global__ __launch_bounds__(256) void scan_sum_kernel(
    const int* __restrict__ deg, int* __restrict__ bsum)
{
    __shared__ int sd[256];
    const int b = blockIdx.x, t = threadIdx.x;
    const int base = b * SCAN_CHUNK;
    int s = 0;
    #pragma unroll
    for (int i = 0; i < SCAN_CHUNK / 256; i++) {
        const int idx = base + t + i * 256;
        s += (idx < N_NODES) ? deg[idx] : 0;
    }
    sd[t] = s; __syncthreads();
    for (int off = 128; off > 0; off >>= 1) {
        if (t < off) sd[t] += sd[t + off];
        __syncthreads();
    }
    if (t == 0) bsum[b] = sd[0];
}

__global__ __launch_bounds__(256) void scan_block_kernel(
    const int* __restrict__ bsum, int* __restrict__ boff, int* __restrict__ offs)
{
    __shared__ int sd[256];
    const int t = threadIdx.x;
    const int v = (t < NBLK_SCAN) ? bsum[t] : 0;
    sd[t] = v; __syncthreads();
    for (int off = 1; off < 256; off <<= 1) {
        const int u = (t >= off) ? sd[t - off] : 0;
        __syncthreads();
        sd[t] += u;
        __syncthreads();
    }
    if (t < NBLK_SCAN) boff[t] = sd[t] - v;
    if (t == 0) offs[N_NODES] = N_EDGES;
}

__global__ __launch_bounds__(256) void scan_scatter_kernel(
    const int* __restrict__ deg, const int* __restrict__ boff, int* __restrict__ offs)
{
    __shared__ int sd[256];
    const int b = blockIdx.x, t = threadIdx.x;
    const int base = b * SCAN_CHUNK + t * 4;
    int d0 = 0, d1 = 0, d2 = 0, d3 = 0;
    if (base + 0 < N_NODES) d0 = deg[base + 0];
    if (base + 1 < N_NODES) d1 = deg[base + 1];
    if (base + 2 < N_NODES) d2 = deg[base + 2];
    if (base + 3 < N_NODES) d3 = deg[base + 3];
    const int ts = d0 + d1 + d2 + d3;
    sd[t] = ts; __syncthreads();
    for (int off = 1; off < 256; off <<= 1) {
        const int u = (t >= off) ? sd[t - off] : 0;
        __syncthreads();
        sd[t] += u;
        __syncthreads();
    }
    const int excl = sd[t] - ts + boff[b];
    if (base + 0 < N_NODES) offs[base + 0] = excl;
    if (base + 1 < N_NODES) offs[base + 1] = excl + d0;
    if (base + 2 < N_NODES) offs[base + 2] = excl + d0 + d1;
    if (base + 3 < N_NODES) offs[base + 3] = excl + d0 + d1 + d2;
}

__global__ __launch_bounds__(256) void bucket_kernel(
    const int* __restrict__ src, const int* __restrict__ dst,
    int* __restrict__ cursor, int* __restrict__ csr_src)
{
    const int e = blockIdx.x * 256 + threadIdx.x;
    if (e < N_EDGES) {
        const int pos = atomicAdd(&cursor[dst[e]], 1);
        csr_src[pos] = src[e];
    }
}

// ===========================================================================
// Embed: h0 = relu(bn(x @ W + b)) via split-bf16 MFMA.
// x tile converted on load into A-fragment-order LDS (lane-linear 16B slots).
// W prepacked B-frags loaded straight from global.
// ===========================================================================
__global__ __launch_bounds__(256) void embed_kernel(
    const float* __restrict__ x, const unsigned short* __restrict__ wpe,
    const float* __restrict__ bias,
    const float* __restrict__ bn_g, const float* __restrict__ bn_b,
    const float* __restrict__ bn_m, const float* __restrict__ bn_v,
    float* __restrict__ h)
{
    __shared__ __align__(16) short Abuf[4 * 4 * 2 * 64 * 8];   // 32 KB
    __shared__ float Ztmp[TILE_N * ZS];                        // 17408 B
    __shared__ float BNs[128];
    const int t = threadIdx.x, lane = t & 63, w = t >> 6;
    const int base = blockIdx.x * TILE_N;

    if (t < 64) {
        const float s = bn_g[t] * rsqrtf(bn_v[t] + BN_EPS);
        BNs[t] = s;
        BNs[64 + t] = bias[t] * s + bn_b[t] - bn_m[t] * s;
    }
    // stage + hi/lo convert x tile into A-frag order
    #pragma unroll
    for (int i = 0; i < 8; i++) {
        const int idx = t + i * 256;                 // 0..2047
        const int n = idx >> 5, k4 = idx & 31;
        const float4 v = *(const float4*)(x + (size_t)(base + n) * IN_DIM + k4 * 4);
        uint2 hi, lo; cvt4(v, hi, lo);
        const int s = k4 >> 3, lc = (n & 15) + 16 * ((k4 >> 1) & 3);
        const int half = k4 & 1, wm = n >> 4;
        *(uint2*)&Abuf[(((wm * 4 + s) * 2 + 0) * 64 + lc) * 8 + half * 4] = hi;
        *(uint2*)&Abuf[(((wm * 4 + s) * 2 + 1) * 64 + lc) * 8 + half * 4] = lo;
    }
    __syncthreads();

    const bf16x8* A = (const bf16x8*)Abuf;
    const bf16x8* B = (const bf16x8*)wpe;
    bf16x8 ah[4], al[4];
    #pragma unroll
    for (int s = 0; s < 4; s++) {
        ah[s] = A[((w * 4 + s) * 2 + 0) * 64 + lane];
        al[s] = A[((w * 4 + s) * 2 + 1) * 64 + lane];
    }
    const int q = lane >> 4, c = lane & 15;
    #pragma unroll
    for (int ct = 0; ct < 4; ct++) {
        f32x4 acc = {0.f, 0.f, 0.f, 0.f};
        #pragma unroll
        for (int s = 0; s < 4; s++) {
            const bf16x8 bh = B[(ct << 9) + (s << 7) + lane];
            const bf16x8 bl = B[(ct << 9) + (s << 7) + 64 + lane];
            acc = MFMA16(ah[s], bh, acc);
            acc = MFMA16(ah[s], bl, acc);
            acc = MFMA16(al[s], bh, acc);
        }
        const int n = ct * 16 + c;
        const float sc = BNs[n], sh = BNs[64 + n];
        #pragma unroll
        for (int r = 0; r < 4; r++)
            Ztmp[(w * 16 + q * 4 + r) * ZS + n] = fmaxf(acc[r] * sc + sh, 0.f);
    }
    __syncthreads();
    #pragma unroll
    for (int i = 0; i < 4; i++) {
        const int idx = t + i * 256, n = idx >> 4, k4 = idx & 15;
        *(float4*)(h + (size_t)(base + n) * HID + k4 * 4) =
            *(const float4*)(&Ztmp[n * ZS + k4 * 4]);
    }
}

// ===========================================================================
// Fused GIN layer: r7's gather (branch-free clamped 4-deep, LDS edge cache)
// -> split-bf16 MFMA GEMM1 -> bn/relu -> re-split -> MFMA GEMM2 -> bn/relu.
// Weights prepacked B-frags from global; A-frags in lane-linear LDS.
// ===========================================================================
__global__ __launch_bounds__(256) void agg_mlp_kernel(
    const float* __restrict__ hin, float* __restrict__ hout,
    const int* __restrict__ offs, const int* __restrict__ csr,
    const unsigned short* __restrict__ wp1, const unsigned short* __restrict__ wp2,
    const float* __restrict__ b1, const float* __restrict__ g1,
    const float* __restrict__ bb1, const float* __restrict__ m1, const float* __restrict__ v1,
    const float* __restrict__ b2, const float* __restrict__ g2,
    const float* __restrict__ bb2, const float* __restrict__ m2, const float* __restrict__ v2)
{
    __shared__ __align__(16) short Abuf[4 * 2 * 2 * 64 * 8];   // 16 KB
    __shared__ float Ztmp[TILE_N * ZS];                        // 17408 B
    __shared__ int   OF[TILE_N + 1];
    __shared__ int   EIDX[ECAP];                               // 4 KB
    __shared__ float BNs[256];
    const int t = threadIdx.x, lane = t & 63, w = t >> 6;
    const int sub = lane >> 4, cq = lane & 15;
    const int base = blockIdx.x * TILE_N;

    if (t < 64) {
        const float sa = g1[t] * rsqrtf(v1[t] + BN_EPS);
        BNs[t] = sa; BNs[64 + t] = b1[t] * sa + bb1[t] - m1[t] * sa;
        const float sb = g2[t] * rsqrtf(v2[t] + BN_EPS);
        BNs[128 + t] = sb; BNs[192 + t] = b2[t] * sb + bb2[t] - m2[t] * sb;
    }
    if (t <= TILE_N) OF[t] = offs[base + t];
    const int segStart = offs[base];
    const int segEnd   = offs[base + TILE_N];
    for (int i = t; i < segEnd - segStart; i += 256)
        if (i < ECAP) EIDX[i] = csr[segStart + i];
    __syncthreads();

    // gather -> A-frag hi/lo writes
    const float* __restrict__ hc = hin + cq * 4;
    #pragma unroll
    for (int p = 0; p < 4; p++) {
        const int mloc = p * 4 + sub, nl = w * 16 + mloc;
        const int e0 = OF[nl], e1 = OF[nl + 1];
        float4 acc = *(const float4*)(hin + (size_t)(base + nl) * HID + cq * 4);
        if (e0 < e1) {
            const int e1m = e1 - 1;
            for (int e = e0; e < e1; e += 4) {
                const int ea = e;
                const int eb = (e + 1 < e1) ? e + 1 : e1m;
                const int ec = (e + 2 < e1) ? e + 2 : e1m;
                const int ed = (e + 3 < e1) ? e + 3 : e1m;
                const int la = ea - segStart, lb = eb - segStart;
                const int lc2 = ec - segStart, ld = ed - segStart;
                const int s0 = (la < ECAP) ? EIDX[la] : csr[ea];
                const int s1 = (lb < ECAP) ? EIDX[lb] : csr[eb];
                const int s2 = (lc2 < ECAP) ? EIDX[lc2] : csr[ec];
                const int s3 = (ld < ECAP) ? EIDX[ld] : csr[ed];
                const float4 v0 = *(const float4*)(hc + (size_t)s0 * HID);
                const float4 v1_ = *(const float4*)(hc + (size_t)s1 * HID);
                const float4 v2_ = *(const float4*)(hc + (size_t)s2 * HID);
                const float4 v3_ = *(const float4*)(hc + (size_t)s3 * HID);
                const float mk1 = (e + 1 < e1) ? 1.f : 0.f;
                const float mk2 = (e + 2 < e1) ? 1.f : 0.f;
                const float mk3 = (e + 3 < e1) ? 1.f : 0.f;
                acc.x += v0.x + mk1 * v1_.x + mk2 * v2_.x + mk3 * v3_.x;
                acc.y += v0.y + mk1 * v1_.y + mk2 * v2_.y + mk3 * v3_.y;
                acc.z += v0.z + mk1 * v1_.z + mk2 * v2_.z + mk3 * v3_.z;
                acc.w += v0.w + mk1 * v1_.w + mk2 * v2_.w + mk3 * v3_.w;
            }
        }
        uint2 hi, lo; cvt4(acc, hi, lo);
        const int s = cq >> 3, lc = mloc + 16 * ((cq >> 1) & 3), half = cq & 1;
        *(uint2*)&Abuf[(((w * 2 + s) * 2 + 0) * 64 + lc) * 8 + half * 4] = hi;
        *(uint2*)&Abuf[(((w * 2 + s) * 2 + 1) * 64 + lc) * 8 + half * 4] = lo;
    }
    __syncthreads();

    const bf16x8* A = (const bf16x8*)Abuf;
    const int q = lane >> 4, c = lane & 15;

    // GEMM1
    {
        const bf16x8 a0h = A[((w * 2 + 0) * 2 + 0) * 64 + lane];
        const bf16x8 a0l = A[((w * 2 + 0) * 2 + 1) * 64 + lane];
        const bf16x8 a1h = A[((w * 2 + 1) * 2 + 0) * 64 + lane];
        const bf16x8 a1l = A[((w * 2 + 1) * 2 + 1) * 64 + lane];
        const bf16x8* B = (const bf16x8*)wp1;
        #pragma unroll
        for (int ct = 0; ct < 4; ct++) {
            const bf16x8 b0h = B[(ct << 8) + lane];
            const bf16x8 b0l = B[(ct << 8) + 64 + lane];
            const bf16x8 b1h_ = B[(ct << 8) + 128 + lane];
            const bf16x8 b1l_ = B[(ct << 8) + 192 + lane];
            f32x4 acc = {0.f, 0.f, 0.f, 0.f};
            acc = MFMA16(a0h, b0h, acc);
            acc = MFMA16(a0h, b0l, acc);
            acc = MFMA16(a0l, b0h, acc);
            acc = MFMA16(a1h, b1h_, acc);
            acc = MFMA16(a1h, b1l_, acc);
            acc = MFMA16(a1l, b1h_, acc);
            const int n = ct * 16 + c;
            const float sc = BNs[n], sh = BNs[64 + n];
            #pragma unroll
            for (int r = 0; r < 4; r++)
                Ztmp[(w * 16 + q * 4 + r) * ZS + n] = fmaxf(acc[r] * sc + sh, 0.f);
        }
    }
    __syncthreads();    // Ztmp complete; Abuf free

    // re-split t1 into A-frags
    {
        const int m = t >> 2;
        #pragma unroll
        for (int d = 0; d < 4; d++) {
            const int k4 = (t & 3) * 4 + d;
            const float4 v = *(const float4*)(&Ztmp[m * ZS + k4 * 4]);
            uint2 hi, lo; cvt4(v, hi, lo);
            const int s = k4 >> 3, lc = (m & 15) + 16 * ((k4 >> 1) & 3);
            const int half = k4 & 1, wm = m >> 4;
            *(uint2*)&Abuf[(((wm * 2 + s) * 2 + 0) * 64 + lc) * 8 + half * 4] = hi;
            *(uint2*)&Abuf[(((wm * 2 + s) * 2 + 1) * 64 + lc) * 8 + half * 4] = lo;
        }
    }
    __syncthreads();

    // GEMM2
    {
        const bf16x8 a0h = A[((w * 2 + 0) * 2 + 0) * 64 + lane];
        const bf16x8 a0l = A[((w * 2 + 0) * 2 + 1) * 64 + lane];
        const bf16x8 a1h = A[((w * 2 + 1) * 2 + 0) * 64 + lane];
        const bf16x8 a1l = A[((w * 2 + 1) * 2 + 1) * 64 + lane];
        const bf16x8* B = (const bf16x8*)wp2;
        #pragma unroll
        for (int ct = 0; ct < 4; ct++) {
            const bf16x8 b0h = B[(ct << 8) + lane];
            const bf16x8 b0l = B[(ct << 8) + 64 + lane];
            const bf16x8 b1h_ = B[(ct << 8) + 128 + lane];
            const bf16x8 b1l_ = B[(ct << 8) + 192 + lane];
            f32x4 acc = {0.f, 0.f, 0.f, 0.f};
            acc = MFMA16(a0h, b0h, acc);
            acc = MFMA16(a0h, b0l, acc);
            acc = MFMA16(a0l, b0h, acc);
            acc = MFMA16(a1h, b1h_, acc);
            acc = MFMA16(a1h, b1l_, acc);
            acc = MFMA16(a1l, b1h_, acc);
            const int n = ct * 16 + c;
            const float sc = BNs[128 + n], sh = BNs[192 + n];
            #pragma unroll
            for (int r = 0; r < 4; r++)
                Ztmp[(w * 16 + q * 4 + r) * ZS + n] = fmaxf(acc[r] * sc + sh, 0.f);
        }
    }
    __syncthreads();

    #pragma unroll
    for (int i = 0; i < 4; i++) {
        const int idx = t + i * 256, n = idx >> 4, k4 = idx & 15;
        *(float4*)(hout + (size_t)(base + n) * HID + k4 * 4) =
            *(const float4*)(&Ztmp[n * ZS + k4 * 4]);
    }
}

// ===========================================================================
// Pool (unchanged)
// ===========================================================================
__global__ __launch_bounds__(256) void pool_kernel(
    const float* __restrict__ h, const int* __restrict__ batch,
    float* __restrict__ pooled, float* __restrict__ cnt)
{
    const int CHUNK = 256;
    const int wid = (blockIdx.x * 256 + threadIdx.x) >> 6;
    const int lane = threadIdx.x & 63;
    const int start = wid * CHUNK;
    if (start >= N_NODES) return;
    const int end = (start + CHUNK < N_NODES) ? (start + CHUNK) : N_NODES;
    int cur = batch[start];
    float acc = 0.f, c = 0.f;
    for (int n = start; n < end; n++) {
        const int g = batch[n];
        if (g != cur) {
            atomicAdd(&pooled[(size_t)cur * HID + lane], acc);
            if (lane == 0) atomicAdd(&cnt[cur], c);
            cur = g; acc = 0.f; c = 0.f;
        }
        acc += h[(size_t)n * HID + lane];
        c += 1.f;
    }
    atomicAdd(&pooled[(size_t)cur * HID + lane], acc);
    if (lane == 0) atomicAdd(&cnt[cur], c);
}

// ===========================================================================
// Classifier (unchanged)
// ===========================================================================
__global__ __launch_bounds__(64) void cls_kernel(
    const float* __restrict__ pooled, const float* __restrict__ cnt,
    const float* __restrict__ w1, const float* __restrict__ b1,
    const float* __restrict__ w2, const float* __restrict__ b2,
    float* __restrict__ out)
{
    const int g = blockIdx.x;
    const int lane = threadIdx.x;
    const float c = cnt[g];
    const float p = pooled[(size_t)g * HID + lane] / fmaxf(c, 1.f);
    float acc = (lane < 32) ? b1[lane] : 0.f;
    #pragma unroll
    for (int k = 0; k < 64; k++) {
        const float pk = __shfl(p, k, 64);
        if (lane < 32) acc += pk * w1[k * 32 + lane];
    }
    const float hmid = fmaxf(acc, 0.f);
    float acc2 = (lane < NCLS) ? b2[lane] : 0.f;
    #pragma unroll
    for (int k = 0; k < 32; k++) {
        const float hk = __shfl(hmid, k, 64);
        if (lane < NCLS) acc2 += hk * w2[k * NCLS + lane];
    }
    if (lane < NCLS) out[(size_t)g * NCLS + lane] = acc2;
}

// ===========================================================================
extern "C" void kernel_launch(void* const* d_in, const int* in_sizes, int n_in,
                              void* d_out, int out_size, void* d_ws, size_t ws_size,
                              hipStream_t stream) {
    const float* x     = (const float*)d_in[0];
    const int*   ei    = (const int*)d_in[1];
    const int*   batch = (const int*)d_in[2];
    const float* emb_w = (const float*)d_in[3];
    const float* emb_b = (const float*)d_in[4];
    const float* ibn_g = (const float*)d_in[5];
    const float* ibn_b = (const float*)d_in[6];
    const float* ibn_m = (const float*)d_in[7];
    const float* ibn_v = (const float*)d_in[8];
    const float* fc1_w = (const float*)d_in[9];
    const float* fc1_b = (const float*)d_in[10];
    const float* mbn_g = (const float*)d_in[11];
    const float* mbn_b = (const float*)d_in[12];
    const float* mbn_m = (const float*)d_in[13];
    const float* mbn_v = (const float*)d_in[14];
    const float* fc2_w = (const float*)d_in[15];
    const float* fc2_b = (const float*)d_in[16];
    const float* obn_g = (const float*)d_in[17];
    const float* obn_b = (const float*)d_in[18];
    const float* obn_m = (const float*)d_in[19];
    const float* obn_v = (const float*)d_in[20];
    const float* cls1w = (const float*)d_in[21];
    const float* cls1b = (const float*)d_in[22];
    const float* cls2w = (const float*)d_in[23];
    const float* cls2b = (const float*)d_in[24];

    float* h0     = (float*)d_ws;
    float* h1     = h0 + (size_t)N_NODES * HID;
    float* pooled = h1 + (size_t)N_NODES * HID;
    float* cnt    = pooled + NGRAPH * HID;
    int*   deg    = (int*)(cnt + NGRAPH);
    int*   offs   = deg + N_NODES;
    int*   bsum   = offs + (N_NODES + 1);
    int*   boff   = bsum + NBLK_SCAN;
    int*   csr    = boff + NBLK_SCAN;
    unsigned short* wpe = (unsigned short*)(csr + N_EDGES);   // 16384
    unsigned short* wpf = wpe + 16384;                        // 49152

    const int* src = ei;
    const int* dst = ei + N_EDGES;

    // weight prep (B-fragment packing, hi/lo planes)
    prep_emb_kernel<<<64, 256, 0, stream>>>(emb_w, wpe);
    prep_fc_kernel<<<192, 256, 0, stream>>>(fc1_w, fc2_w, wpf);

    // CSR build
    hipMemsetAsync(deg, 0, N_NODES * sizeof(int), stream);
    hipMemsetAsync(pooled, 0, (size_t)(NGRAPH * HID + NGRAPH) * sizeof(float), stream);
    hist_kernel<<<(N_EDGES + 255) / 256, 256, 0, stream>>>(dst, deg);
    scan_sum_kernel<<<NBLK_SCAN, 256, 0, stream>>>(deg, bsum);
    scan_block_kernel<<<1, 256, 0, stream>>>(bsum, boff, offs);
    scan_scatter_kernel<<<NBLK_SCAN, 256, 0, stream>>>(deg, boff, offs);
    hipMemcpyAsync(deg, offs, N_NODES * sizeof(int), hipMemcpyDeviceToDevice, stream);
    bucket_kernel<<<(N_EDGES + 255) / 256, 256, 0, stream>>>(src, dst, deg, csr);

    // network
    const int gemm_blocks = N_NODES / TILE_N;   // 3125
    embed_kernel<<<gemm_blocks, 256, 0, stream>>>(x, wpe, emb_b,
                                                  ibn_g, ibn_b, ibn_m, ibn_v, h0);

    const float* hin = h0;
    float* hout = h1;
    for (int i = 0; i < 3; i++) {
        agg_mlp_kernel<<<gemm_blocks, 256, 0, stream>>>(
            hin, hout, offs, csr,
            wpf + (size_t)(i * 2 + 0) * 8192, wpf + (size_t)(i * 2 + 1) * 8192,
            fc1_b + i * HID, mbn_g + i * HID, mbn_b + i * HID, mbn_m + i * HID, mbn_v + i * HID,
            fc2_b + i * HID, obn_g + i * HID, obn_b + i * HID, obn_m + i * HID, obn_v + i * HID);
        const float* tmp = hin; hin = hout; hout = (float*)tmp;
    }

    const int pool_waves = (N_NODES + 255) / 256;
    pool_kernel<<<(pool_waves + 3) / 4, 256, 0, stream>>>(h1, batch, pooled, cnt);

    cls_kernel<<<NGRAPH, 64, 0, stream>>>(pooled, cnt, cls1w, cls1b, cls2w, cls2b,
                                          (float*)d_out);
}